// Round 8
// baseline (248.355 us; speedup 1.0000x reference)
//
#include <hip/hip_runtime.h>
#include <hip/hip_fp16.h>
#include <math.h>

#define DIM   256
#define NLVL  5
#define NB    2048           // pass1/pass2 blocks (8192 waves)
#define NW    (NB*4)

struct Ptrs {
  const float* p[NLVL];
  const float* W[NLVL];
  const float* b[NLVL];
};

// ---- pass 1: logits + fused online-softmax partials + fp16 copy of p ----
__global__ __launch_bounds__(256) void k_pass1(Ptrs pt, __half* __restrict__ pc,
                                               float* __restrict__ logits,
                                               float2* __restrict__ part,
                                               int N, int use_pc)
{
  const int lane = threadIdx.x & 63;
  const int wid  = threadIdx.x >> 6;

  float4 wf[NLVL];
  float  bias[NLVL], m[NLVL], s[NLVL];
  #pragma unroll
  for (int l = 0; l < NLVL; l++) {
    wf[l]   = *reinterpret_cast<const float4*>(pt.W[l] + lane * 4);
    bias[l] = *pt.b[l];
    m[l]    = -INFINITY;
    s[l]    = 0.f;
  }

  const int gw  = blockIdx.x * 4 + wid;
  const int off = lane * 4;

  for (int n = gw; n < N; n += NW) {
    float4 pv[NLVL];
    float  d[NLVL];
    #pragma unroll
    for (int l = 0; l < NLVL; l++) {
      pv[l] = *reinterpret_cast<const float4*>(pt.p[l] + (size_t)n * DIM + off);
      d[l]  = pv[l].x * wf[l].x + pv[l].y * wf[l].y + pv[l].z * wf[l].z + pv[l].w * wf[l].w;
    }
    if (use_pc) {                              // fp16 copy: 8 B/lane/level, coalesced
      #pragma unroll
      for (int l = 0; l < NLVL; l++) {
        union { __half2 h2[2]; uint2 u; } cv;
        cv.h2[0] = __floats2half2_rn(pv[l].x, pv[l].y);
        cv.h2[1] = __floats2half2_rn(pv[l].z, pv[l].w);
        *reinterpret_cast<uint2*>(pc + ((size_t)l * N + n) * DIM + off) = cv.u;
      }
    }
    #pragma unroll
    for (int o = 32; o; o >>= 1) {             // 5 independent reduce chains
      #pragma unroll
      for (int l = 0; l < NLVL; l++) d[l] += __shfl_xor(d[l], o);
    }
    #pragma unroll
    for (int l = 0; l < NLVL; l++) d[l] += bias[l];

    float sv = d[0];
    sv = (lane == 1) ? d[1] : sv;
    sv = (lane == 2) ? d[2] : sv;
    sv = (lane == 3) ? d[3] : sv;
    sv = (lane == 4) ? d[4] : sv;
    if (lane < NLVL) logits[(size_t)lane * N + n] = sv;

    #pragma unroll
    for (int l = 0; l < NLVL; l++) {           // online softmax (lane-redundant)
      float Mn = fmaxf(m[l], d[l]);
      s[l] = s[l] * __expf(m[l] - Mn) + __expf(d[l] - Mn);
      m[l] = Mn;
    }
  }

  __shared__ float smM[4][NLVL], smS[4][NLVL];
  if (lane == 0) {
    #pragma unroll
    for (int l = 0; l < NLVL; l++) { smM[wid][l] = m[l]; smS[wid][l] = s[l]; }
  }
  __syncthreads();
  if (threadIdx.x < NLVL) {
    const int l = threadIdx.x;
    float M = smM[0][l], S = smS[0][l];
    #pragma unroll
    for (int i = 1; i < 4; i++) {
      float Mn = fmaxf(M, smM[i][l]);
      if (Mn > -INFINITY) { S = S * __expf(M - Mn) + smS[i][l] * __expf(smM[i][l] - Mn); M = Mn; }
    }
    part[l * NB + blockIdx.x] = make_float2(M, S);
  }
}

// ---- combine NB partials per level -> (M, S) ----
__global__ __launch_bounds__(320) void k_reduce(const float2* __restrict__ part,
                                                float2* __restrict__ stats)
{
  const int lvl  = threadIdx.x >> 6;
  const int lane = threadIdx.x & 63;
  float m = -INFINITY, s = 0.f;
  for (int i = lane; i < NB; i += 64) {
    float2 ps = part[lvl * NB + i];
    float Mn = fmaxf(m, ps.x);
    if (Mn > -INFINITY) { s = s * __expf(m - Mn) + ps.y * __expf(ps.x - Mn); m = Mn; }
  }
  #pragma unroll
  for (int o = 32; o; o >>= 1) {
    float mo = __shfl_xor(m, o), so = __shfl_xor(s, o);
    float Mn = fmaxf(m, mo);
    if (Mn > -INFINITY) { s = s * __expf(m - Mn) + so * __expf(mo - Mn); m = Mn; }
  }
  if (lane == 0) stats[lvl] = make_float2(m, s);
}

// ---- pass 2 (fp16 path): weights + fused output from the fp16 copy ----
__global__ __launch_bounds__(256) void k_pass2_h(const __half* __restrict__ pc,
                                                 const float* __restrict__ logits,
                                                 const float2* __restrict__ stats,
                                                 float* __restrict__ out, int N)
{
  const int lane = threadIdx.x & 63;
  const int wid  = threadIdx.x >> 6;
  float M[NLVL], Si[NLVL];
  #pragma unroll
  for (int l = 0; l < NLVL; l++) { float2 st = stats[l]; M[l] = st.x; Si[l] = 1.f / st.y; }

  const int gw  = blockIdx.x * 4 + wid;
  const int off = lane * 4;
  for (int n = gw; n < N; n += NW) {
    float wl[NLVL], t = 0.f;
    #pragma unroll
    for (int l = 0; l < NLVL; l++) {
      float e = __expf(logits[(size_t)l * N + n] - M[l]) * Si[l];
      wl[l] = e; t += e;
    }
    const float inv = 1.f / t;
    float4 acc = make_float4(0.f, 0.f, 0.f, 0.f);
    #pragma unroll
    for (int l = 0; l < NLVL; l++) {
      union { uint2 u; __half2 h2[2]; } cv;
      cv.u = *reinterpret_cast<const uint2*>(pc + ((size_t)l * N + n) * DIM + off);
      float2 f01 = __half22float2(cv.h2[0]);
      float2 f23 = __half22float2(cv.h2[1]);
      float c = wl[l] * inv;
      acc.x += c * f01.x; acc.y += c * f01.y; acc.z += c * f23.x; acc.w += c * f23.y;
    }
    *reinterpret_cast<float4*>(out + (size_t)n * DIM + off) = acc;
  }
}

// ---- pass 2 (fp32 fallback): re-read original p ----
__global__ __launch_bounds__(256) void k_pass2_f(Ptrs pt, const float* __restrict__ logits,
                                                 const float2* __restrict__ stats,
                                                 float* __restrict__ out, int N)
{
  const int lane = threadIdx.x & 63;
  const int wid  = threadIdx.x >> 6;
  float M[NLVL], Si[NLVL];
  #pragma unroll
  for (int l = 0; l < NLVL; l++) { float2 st = stats[l]; M[l] = st.x; Si[l] = 1.f / st.y; }

  const int gw  = blockIdx.x * 4 + wid;
  const int off = lane * 4;
  for (int n = gw; n < N; n += NW) {
    float wl[NLVL], t = 0.f;
    #pragma unroll
    for (int l = 0; l < NLVL; l++) {
      float e = __expf(logits[(size_t)l * N + n] - M[l]) * Si[l];
      wl[l] = e; t += e;
    }
    const float inv = 1.f / t;
    float4 acc = make_float4(0.f, 0.f, 0.f, 0.f);
    #pragma unroll
    for (int l = 0; l < NLVL; l++) {
      float4 pv = *reinterpret_cast<const float4*>(pt.p[l] + (size_t)n * DIM + off);
      float c = wl[l] * inv;
      acc.x += c * pv.x; acc.y += c * pv.y; acc.z += c * pv.z; acc.w += c * pv.w;
    }
    *reinterpret_cast<float4*>(out + (size_t)n * DIM + off) = acc;
  }
}

extern "C" void kernel_launch(void* const* d_in, const int* in_sizes, int n_in,
                              void* d_out, int out_size, void* d_ws, size_t ws_size,
                              hipStream_t stream)
{
  Ptrs pt;
  for (int l = 0; l < NLVL; l++) {
    pt.p[l] = (const float*)d_in[l];
    pt.W[l] = (const float*)d_in[5 + 2 * l];
    pt.b[l] = (const float*)d_in[6 + 2 * l];
  }
  const int N = in_sizes[0] / DIM;             // 100000

  char* ws = (char*)d_ws;
  size_t logits_bytes = (((size_t)NLVL * N * sizeof(float)) + 255) & ~(size_t)255;
  size_t part_bytes   = (((size_t)NLVL * NB * sizeof(float2)) + 255) & ~(size_t)255;
  size_t stats_bytes  = 256;
  float*  logits = (float*)ws;
  float2* part   = (float2*)(ws + logits_bytes);
  float2* stats  = (float2*)(ws + logits_bytes + part_bytes);
  size_t  pc_off = logits_bytes + part_bytes + stats_bytes;
  size_t  pc_bytes = (size_t)NLVL * N * DIM * sizeof(__half);   // 256 MB
  __half* pc = (__half*)(ws + pc_off);
  const int use_pc = (ws_size >= pc_off + pc_bytes) ? 1 : 0;

  k_pass1 <<<NB, 256, 0, stream>>>(pt, pc, logits, part, N, use_pc);
  k_reduce<<<1,  320, 0, stream>>>(part, stats);
  if (use_pc)
    k_pass2_h<<<NB, 256, 0, stream>>>(pc, logits, stats, (float*)d_out, N);
  else
    k_pass2_f<<<NB, 256, 0, stream>>>(pt, logits, stats, (float*)d_out, N);
}

// Round 9
// 224.334 us; speedup vs baseline: 1.1071x; 1.1071x over previous
//
#include <hip/hip_runtime.h>
#include <math.h>

#define DIM   256
#define NLVL  5
#define NB    2048           // pass1 blocks (8192 waves; 6250 chunks -> 1 round)
#define NSB   64             // stats blocks per level

struct Ptrs {
  const float* p[NLVL];
  const float* W[NLVL];
  const float* b[NLVL];
};

// ---- pass 1: logits only. Chunk = 16 rows x 5 levels per wave.
//      Each 64B logit sector is written by exactly ONE wave as ONE full store.
__global__ __launch_bounds__(256) void k_pass1(Ptrs pt, float* __restrict__ logits, int N)
{
  const int lane = threadIdx.x & 63;
  const int wid  = threadIdx.x >> 6;

  float4 wf[NLVL];
  float  bias[NLVL];
  #pragma unroll
  for (int l = 0; l < NLVL; l++) {
    wf[l]   = *reinterpret_cast<const float4*>(pt.W[l] + lane * 4);
    bias[l] = *pt.b[l];
  }

  const int gw  = blockIdx.x * 4 + wid;
  const int nw  = NB * 4;
  const int off = lane * 4;
  const int nch = N >> 4;                      // 6250 chunks of 16 rows

  const int g = lane >> 3;                     // octet index 0..7
  const int e = lane & 7;                      // index within octet

  for (int c = gw; c < nch; c += nw) {
    const size_t n0 = (size_t)c << 4;
    #pragma unroll
    for (int l = 0; l < NLVL; l++) {
      const float* base = pt.p[l] + n0 * DIM + off;
      float v[8], u[8];
      #pragma unroll
      for (int j = 0; j < 8; j++) {            // 16 row-dots (rows n0+j, n0+8+j)
        float4 a = *reinterpret_cast<const float4*>(base + j * DIM);
        v[j] = a.x * wf[l].x + a.y * wf[l].y + a.z * wf[l].z + a.w * wf[l].w;
        float4 b2 = *reinterpret_cast<const float4*>(base + (j + 8) * DIM);
        u[j] = b2.x * wf[l].x + b2.y * wf[l].y + b2.z * wf[l].z + b2.w * wf[l].w;
      }
      // exchange-combine (verified in R1): after masks 32/16/8, octet g holds
      // row g's partial (v) and row 8+g's partial (u) over same-e lanes.
      #pragma unroll
      for (int step = 0; step < 3; step++) {
        const int mm   = 32 >> step;
        const int half = 4 >> step;
        #pragma unroll
        for (int j = 0; j < half; j++) {
          float sendv = (lane & mm) ? v[j] : v[j + half];
          float keepv = (lane & mm) ? v[j + half] : v[j];
          v[j] = keepv + __shfl_xor(sendv, mm);
          float sendu = (lane & mm) ? u[j] : u[j + half];
          float keepu = (lane & mm) ? u[j + half] : u[j];
          u[j] = keepu + __shfl_xor(sendu, mm);
        }
      }
      float dA = v[0], dB = u[0];
      dA += __shfl_xor(dA, 4); dB += __shfl_xor(dB, 4);
      dA += __shfl_xor(dA, 2); dB += __shfl_xor(dB, 2);
      dA += __shfl_xor(dA, 1); dB += __shfl_xor(dB, 1);
      dA += bias[l]; dB += bias[l];
      // ONE 64B-aligned full-sector store from 16 lanes (e<2):
      // lane 8g+e writes row n0 + g + 8e.
      float sv = (e == 0) ? dA : dB;
      if (e < 2)
        logits[(size_t)l * N + n0 + g + (e << 3)] = sv;
    }
  }
}

// ---- stats A: per-(level,block) online-softmax partials over logits (2 MB) ----
__global__ __launch_bounds__(256) void k_stats(const float* __restrict__ logits,
                                               float2* __restrict__ part, int N)
{
  const int lvl = blockIdx.y;
  const float* __restrict__ lg = logits + (size_t)lvl * N;
  float m = -INFINITY, s = 0.f;
  for (int i = blockIdx.x * 256 + threadIdx.x; i < N; i += NSB * 256) {
    float d  = lg[i];
    float Mn = fmaxf(m, d);
    s = s * __expf(m - Mn) + __expf(d - Mn);
    m = Mn;
  }
  const int lane = threadIdx.x & 63;
  const int wid  = threadIdx.x >> 6;
  #pragma unroll
  for (int o = 32; o; o >>= 1) {
    float mo = __shfl_xor(m, o), so = __shfl_xor(s, o);
    float Mn = fmaxf(m, mo);
    if (Mn > -INFINITY) { s = s * __expf(m - Mn) + so * __expf(mo - Mn); m = Mn; }
  }
  __shared__ float smM[4], smS[4];
  if (lane == 0) { smM[wid] = m; smS[wid] = s; }
  __syncthreads();
  if (threadIdx.x == 0) {
    float M = smM[0], Ss = smS[0];
    #pragma unroll
    for (int i = 1; i < 4; i++) {
      float Mn = fmaxf(M, smM[i]);
      if (Mn > -INFINITY) { Ss = Ss * __expf(M - Mn) + smS[i] * __expf(smM[i] - Mn); M = Mn; }
    }
    part[lvl * NSB + blockIdx.x] = make_float2(M, Ss);
  }
}

// ---- stats B: combine NSB partials per level -> (M, S) ----
__global__ __launch_bounds__(320) void k_reduce(const float2* __restrict__ part,
                                                float2* __restrict__ stats)
{
  const int lvl  = threadIdx.x >> 6;
  const int lane = threadIdx.x & 63;
  float m = -INFINITY, s = 0.f;
  if (lane < NSB) { float2 ps = part[lvl * NSB + lane]; m = ps.x; s = ps.y; }
  #pragma unroll
  for (int o = 32; o; o >>= 1) {
    float mo = __shfl_xor(m, o), so = __shfl_xor(s, o);
    float Mn = fmaxf(m, mo);
    if (Mn > -INFINITY) { s = s * __expf(m - Mn) + so * __expf(mo - Mn); m = Mn; }
  }
  if (lane == 0) stats[lvl] = make_float2(m, s);
}

// ---- pass 2: weights + fused output ----
__global__ __launch_bounds__(256) void k_pass2(Ptrs pt, const float* __restrict__ logits,
                                               const float2* __restrict__ stats,
                                               float* __restrict__ out, int N)
{
  const int lane = threadIdx.x & 63;
  const int wid  = threadIdx.x >> 6;
  float M[NLVL], Si[NLVL];
  #pragma unroll
  for (int l = 0; l < NLVL; l++) { float2 st = stats[l]; M[l] = st.x; Si[l] = 1.f / st.y; }

  const int gw  = blockIdx.x * 4 + wid;
  const int nw  = 2048 * 4;
  const int off = lane * 4;
  for (int n = gw; n < N; n += nw) {
    float wl[NLVL], t = 0.f;
    #pragma unroll
    for (int l = 0; l < NLVL; l++) {
      float e = __expf(logits[(size_t)l * N + n] - M[l]) * Si[l];
      wl[l] = e; t += e;
    }
    const float inv = 1.f / t;
    float4 acc = make_float4(0.f, 0.f, 0.f, 0.f);
    #pragma unroll
    for (int l = 0; l < NLVL; l++) {
      float4 pv = *reinterpret_cast<const float4*>(pt.p[l] + (size_t)n * DIM + off);
      float c = wl[l] * inv;
      acc.x += c * pv.x; acc.y += c * pv.y; acc.z += c * pv.z; acc.w += c * pv.w;
    }
    *reinterpret_cast<float4*>(out + (size_t)n * DIM + off) = acc;
  }
}

extern "C" void kernel_launch(void* const* d_in, const int* in_sizes, int n_in,
                              void* d_out, int out_size, void* d_ws, size_t ws_size,
                              hipStream_t stream)
{
  Ptrs pt;
  for (int l = 0; l < NLVL; l++) {
    pt.p[l] = (const float*)d_in[l];
    pt.W[l] = (const float*)d_in[5 + 2 * l];
    pt.b[l] = (const float*)d_in[6 + 2 * l];
  }
  const int N = in_sizes[0] / DIM;             // 100000

  char* ws = (char*)d_ws;
  size_t logits_bytes = (((size_t)NLVL * N * sizeof(float)) + 255) & ~(size_t)255;
  float*  logits = (float*)ws;
  float2* part   = (float2*)(ws + logits_bytes);
  float2* stats  = part + NLVL * NSB;

  k_pass1 <<<NB,              256, 0, stream>>>(pt, logits, N);
  k_stats <<<dim3(NSB, NLVL), 256, 0, stream>>>(logits, part, N);
  k_reduce<<<1,               320, 0, stream>>>(part, stats);
  k_pass2 <<<2048,            256, 0, stream>>>(pt, logits, stats, (float*)d_out, N);
}